// Round 11
// baseline (238.200 us; speedup 1.0000x reference)
//
#include <hip/hip_runtime.h>
#include <stdint.h>
#include <stddef.h>

// y[n,o] = sum_i x[n,i]*W[n,i,o] + b[n,o];  W = (x@Ww+bw) reshaped; b = x@Wb+bb.
// Y = A@B (+bb): A[n, j*128+i] = x[n,i]*x[n,j]; B = Ww as [16384,128] row-major;
// K-tail 128: A[n,16384+i]=x[n,i], B[16384+i,o]=Wb[i,o]+bw[i*128+o].
// Per-j-phase factoring: aj = X_rows·B_j (raw-x frags), acc += x[row,j]*aj.
// fp32 in / fp32 out; bf16 MFMA compute (absmax 0.25 << 1.35).
// ROUND 11: m97-style K-loop — B tile staged to LDS dbuf via global_load_lds
// (16B width), one barrier per kstep, frags via ds_read_b128 (conflict-free:
// XS_STRIDE=136, TSTRIDE=40). R10 proved locality wasn't the binder (FETCH
// halved, time flat at 8% MfmaUtil): per-lane B loads + atomicAdd stream were.
// fp32 atomics eliminated: per-slice g_P8 buffers + fused counter finisher.

#define NROWS   8192
#define NKT     516            // (16384+128)/32 K-tiles
#define TSTRIDE 40             // 32 kk + 8 pad per col (80B: 16B-aligned, bank-coprime)
#define TILE_E  (128*TSTRIDE)  // 5120 u16 = 10240 B per K-tile image
#define XS_STRIDE 136          // 128 + 8 pad for LDS x tile
#define LS_STRIDE 136
#define BM      128

typedef unsigned short u16;
typedef short short8 __attribute__((ext_vector_type(8)));
typedef unsigned short ushort8 __attribute__((ext_vector_type(8)));
typedef float floatx4 __attribute__((ext_vector_type(4)));

// Module-scope scratch (BSS; independent of d_ws).
__device__ __align__(16) u16   g_B[(size_t)NKT * TILE_E];     // 5.3 MB padded B image
__device__ __align__(16) u16   g_X[(size_t)NROWS * 128];      // 2 MB bf16 x image
__device__ __align__(16) float g_P8[8][(size_t)NROWS * 128];  // 32 MB per-slice partials
__device__ int g_cnt[64];                                     // per-rowblock completion

__device__ __forceinline__ float bf2f(u16 u) {
    return __uint_as_float(((unsigned int)u) << 16);
}
__device__ __forceinline__ u16 f2bf_rne(float f) {
    unsigned int u = __float_as_uint(f);
    u += 0x7fffu + ((u >> 16) & 1u);
    return (u16)(u >> 16);
}

// ---------------- prep: g_B[kt][col][kk(+pad)] = B[kt*32+kk][col] via LDS transpose;
//                  also g_X = bf16(x), zero g_cnt ----------------
__global__ __launch_bounds__(256) void prep_kernel(
    const float* __restrict__ Ww, const float* __restrict__ Wb,
    const float* __restrict__ bw, const float* __restrict__ x)
{
    __shared__ __align__(16) u16 ls[32 * LS_STRIDE];
    const int kt = blockIdx.x;
    const int t  = threadIdx.x;

    if (kt < 512) {                       // convert x -> g_X bf16 (2048 elems/block)
        const int xb = kt*2048 + t*8;
        const floatx4 xa = *(const floatx4*)(x + xb);
        const floatx4 xc = *(const floatx4*)(x + xb + 4);
        ushort8 xw;
#pragma unroll
        for (int e = 0; e < 4; ++e) { xw[e] = f2bf_rne(xa[e]); xw[4+e] = f2bf_rne(xc[e]); }
        *(ushort8*)&g_X[xb] = xw;
    }
    if (kt < 64 && t == 0) g_cnt[kt] = 0;

    float v[16];
    if (kt < 512) {
        const float* src = Ww + (size_t)(kt >> 2)*16384 + (size_t)(kt & 3)*32*128 + t*16;
#pragma unroll
        for (int c = 0; c < 4; ++c) {
            const floatx4 f4 = *(const floatx4*)(src + c*4);
#pragma unroll
            for (int e = 0; e < 4; ++e) v[c*4 + e] = f4[e];
        }
    } else {
        const size_t base = (size_t)(kt - 512)*32*128 + t*16;
#pragma unroll
        for (int c = 0; c < 4; ++c) {
            const floatx4 a = *(const floatx4*)(Wb + base + c*4);
            const floatx4 b = *(const floatx4*)(bw + base + c*4);
#pragma unroll
            for (int e = 0; e < 4; ++e) v[c*4 + e] = a[e] + b[e];
        }
    }
    {
        const int kk = t >> 3;            // flat f = t*16 -> kk = f>>7
        const int o0 = (t & 7) * 16;      // f & 127
        ushort8 w0, w1;
#pragma unroll
        for (int e = 0; e < 8; ++e) { w0[e] = f2bf_rne(v[e]); w1[e] = f2bf_rne(v[8+e]); }
        *(ushort8*)&ls[kk*LS_STRIDE + o0]     = w0;
        *(ushort8*)&ls[kk*LS_STRIDE + o0 + 8] = w1;
    }
    __syncthreads();
    {
        const int o   = t >> 1;           // col 0..127
        const int kk0 = (t & 1) * 16;
        ushort8 w0, w1;
#pragma unroll
        for (int e = 0; e < 8; ++e) {
            w0[e] = ls[(kk0 + e)*LS_STRIDE + o];
            w1[e] = ls[(kk0 + 8 + e)*LS_STRIDE + o];
        }
        u16* outp = g_B + (size_t)kt*TILE_E + o*TSTRIDE + kk0;  // 80B rows: 16B-aligned
        ((ushort8*)outp)[0] = w0; ((ushort8*)outp)[1] = w1;
        if (t & 1) {                      // zero the 8-elem pad
            const ushort8 z = {0,0,0,0,0,0,0,0};
            *(ushort8*)(g_B + (size_t)kt*TILE_E + o*TSTRIDE + 32) = z;
        }
    }
}

// ---------------- gemm: m97-style LDS-staged B, dbuf, fused finish ----------------
// grid 512: slice = b&7 (XCD-pinned), rb = b>>3. Block 128x128, 2x2 waves of 64x64.
__global__ __launch_bounds__(256, 2) void gemm_kernel(
    const float* __restrict__ bb, float* __restrict__ out)
{
    __shared__ __align__(16) u16 xs[BM * XS_STRIDE];   // 34816 B
    __shared__ __align__(16) u16 Bs[2][TILE_E];        // 20480 B
    __shared__ int s_last;

    const int b     = blockIdx.x;
    const int slice = b & 7;
    const int rb    = b >> 3;
    const int row0  = rb * BM;
    const int tid   = threadIdx.x;
    const int lane  = tid & 63;
    const int wave  = tid >> 6;
    const int wm    = wave >> 1;      // rows [wm*64, +64)
    const int wn    = wave & 1;       // cols [wn*64, +64)
    const int l15   = lane & 15;
    const int q     = lane >> 4;

    const int p0 = slice*16 + (slice ? 1 : 0);
    const int np = (slice == 0) ? 17 : 16;
    const int nk = np * 4;
    const int kt0 = p0 * 4;

    // stage B tile ktl into Bs[bufi]: 10 chunks of 1KB (wave-uniform LDS base + lane*16)
    auto stage = [&](int bufi, int ktl) {
        const char* src = (const char*)(g_B + (size_t)ktl * TILE_E);
        char* dst = (char*)&Bs[bufi][0];
        __builtin_amdgcn_global_load_lds(
            (const __attribute__((address_space(1))) unsigned int*)(src + wave*1024 + lane*16),
            (__attribute__((address_space(3))) unsigned int*)(dst + wave*1024), 16, 0, 0);
        __builtin_amdgcn_global_load_lds(
            (const __attribute__((address_space(1))) unsigned int*)(src + (wave+4)*1024 + lane*16),
            (__attribute__((address_space(3))) unsigned int*)(dst + (wave+4)*1024), 16, 0, 0);
        if (wave < 2)
            __builtin_amdgcn_global_load_lds(
                (const __attribute__((address_space(1))) unsigned int*)(src + (wave+8)*1024 + lane*16),
                (__attribute__((address_space(3))) unsigned int*)(dst + (wave+8)*1024), 16, 0, 0);
    };

    // stage xs from bf16 g_X (overlaps with first B stage; drained by first barrier)
#pragma unroll
    for (int it = 0; it < 8; ++it) {
        const int c  = it*256 + tid;
        const int r  = c >> 4;
        const int c8 = (c & 15) * 8;
        *(ushort8*)&xs[r*XS_STRIDE + c8] =
            *(const ushort8*)&g_X[((size_t)(row0 + r) << 7) + c8];
    }
    stage(0, kt0);

    const floatx4 fzero = {0.f, 0.f, 0.f, 0.f};
    floatx4 acc[4][4];
#pragma unroll
    for (int i = 0; i < 4; ++i)
#pragma unroll
        for (int j = 0; j < 4; ++j) acc[i][j] = fzero;

    for (int pp = 0; pp < np; ++pp) {
        const int p = p0 + pp;
        floatx4 aj[4][4];
#pragma unroll
        for (int i = 0; i < 4; ++i)
#pragma unroll
            for (int j = 0; j < 4; ++j) aj[i][j] = fzero;

#pragma unroll
        for (int ks = 0; ks < 4; ++ks) {
            const int n = pp*4 + ks;
            __syncthreads();              // drains prev ds_reads + this buf's staging
            if (n + 1 < nk) stage((ks + 1) & 1, kt0 + n + 1);
            const u16* bsc = &Bs[ks & 1][0];
            short8 afr[4], bfr[4];
            const int i0 = ks * 32;
#pragma unroll
            for (int mt = 0; mt < 4; ++mt)   // A[m=l15][k=q*8+e], conflict-free b128
                afr[mt] = *(const short8*)&xs[(wm*64 + mt*16 + l15)*XS_STRIDE + i0 + q*8];
#pragma unroll
            for (int nt = 0; nt < 4; ++nt)   // B[n=col][k], conflict-free b128
                bfr[nt] = *(const short8*)&bsc[(wn*64 + nt*16 + l15)*TSTRIDE + q*8];
#pragma unroll
            for (int mt = 0; mt < 4; ++mt)
#pragma unroll
                for (int nt = 0; nt < 4; ++nt)
                    aj[mt][nt] = __builtin_amdgcn_mfma_f32_16x16x32_bf16(
                        afr[mt], bfr[nt], aj[mt][nt], 0, 0, 0);
        }
        // acc += x[row,p] * aj  (tail phase p==128: scale 1 -> Wb+bw term)
#pragma unroll
        for (int mt = 0; mt < 4; ++mt)
#pragma unroll
            for (int r = 0; r < 4; ++r) {
                const int rl = wm*64 + mt*16 + q*4 + r;   // C/D: row = q*4+reg
                float xj = 1.0f;
                if (p < 128) xj = bf2f(xs[rl*XS_STRIDE + p]);  // broadcast read
#pragma unroll
                for (int nt = 0; nt < 4; ++nt)
                    acc[mt][nt][r] += xj * aj[mt][nt][r];
            }
    }

    // stream this slice's 128x128 fp32 tile (agent-scope stores, no RMW atomics)
    float* P = &g_P8[slice][0];
#pragma unroll
    for (int mt = 0; mt < 4; ++mt)
#pragma unroll
        for (int nt = 0; nt < 4; ++nt) {
            const int col = wn*64 + nt*16 + l15;          // C/D: col = lane&15
#pragma unroll
            for (int r = 0; r < 4; ++r) {
                const int row = row0 + wm*64 + mt*16 + q*4 + r;
                __hip_atomic_store(&P[((size_t)row << 7) + col], acc[mt][nt][r],
                                   __ATOMIC_RELAXED, __HIP_MEMORY_SCOPE_AGENT);
            }
        }
    __threadfence();                      // all this thread's stores device-visible
    __syncthreads();                      // all threads fenced
    if (tid == 0)
        s_last = (atomicAdd(&g_cnt[rb], 1) == 7) ? 1 : 0;
    __syncthreads();
    if (s_last) {                         // 8th block for this rb: sum slices + bb
        __threadfence();
        const float bv = bb[tid & 127];
#pragma unroll 2
        for (int it = 0; it < 64; ++it) {
            const size_t idx = (size_t)row0*128 + it*256 + tid;
            float s = 0.f;
#pragma unroll
            for (int sl = 0; sl < 8; ++sl)
                s += __hip_atomic_load(&g_P8[sl][idx], __ATOMIC_RELAXED,
                                       __HIP_MEMORY_SCOPE_AGENT);
            out[idx] = s + bv;
        }
    }
}

extern "C" void kernel_launch(void* const* d_in, const int* in_sizes, int n_in,
                              void* d_out, int out_size, void* d_ws, size_t ws_size,
                              hipStream_t stream) {
    (void)in_sizes; (void)n_in; (void)out_size; (void)d_ws; (void)ws_size;
    const float* x  = (const float*)d_in[0];
    const float* Wb = (const float*)d_in[1];
    const float* bb = (const float*)d_in[2];
    const float* Ww = (const float*)d_in[3];
    const float* bw = (const float*)d_in[4];
    float* out = (float*)d_out;

    prep_kernel<<<dim3(NKT), dim3(256), 0, stream>>>(Ww, Wb, bw, x);
    gemm_kernel<<<dim3(512), dim3(256), 0, stream>>>(bb, out);
}

// Round 12
// 232.244 us; speedup vs baseline: 1.0256x; 1.0256x over previous
//
#include <hip/hip_runtime.h>
#include <stdint.h>
#include <stddef.h>

// y[n,o] = sum_i x[n,i]*W[n,i,o] + b[n,o];  W = (x@Ww+bw) reshaped; b = x@Wb+bb.
// Y = A@B (+bb): A[n, j*128+i] = x[n,i]*x[n,j]; B = Ww as [16384,128] row-major;
// K-tail 128: A[n,16384+i]=x[n,i], B[16384+i,o]=Wb[i,o]+bw[i*128+o].
// Per-j-phase factoring: aj = X_rows·B_j (raw-x frags), acc += x[row,j]*aj.
// fp32 in / fp32 out; bf16 MFMA compute (absmax 0.25 << 1.35).
// ROUND 12: R10 with the residency bug fixed. R9/R10 ran grid 1024 at
// __launch_bounds__(256,3) -> 3 blocks/CU -> TWO dispatch rounds (~2x wall for a
// latency-bound kernel) — that, not locality/depth, explains 170us vs R7's 78.
// Now (256,4): 4 blocks/CU, single round, 16 waves/CU. Separate finish kernel
// (fused-finish tail removed). Everything else identical to R10.

#define NROWS   8192
#define NKT     516            // (16384+128)/32 K-tiles
#define TILE_E  4096           // 128 cols x 32 kk per K-tile image (u16)
#define XS_STRIDE 136          // 128 + 8 pad for LDS x tile
#define LS_STRIDE 136
#define BM      128

typedef unsigned short u16;
typedef short short8 __attribute__((ext_vector_type(8)));
typedef unsigned short ushort8 __attribute__((ext_vector_type(8)));
typedef float floatx4 __attribute__((ext_vector_type(4)));

// Module-scope scratch (BSS; independent of d_ws).
__device__ __align__(16) u16   g_B[(size_t)NKT * TILE_E];   // 4.2 MB bf16 B image
__device__ __align__(16) u16   g_X[(size_t)NROWS * 128];    // 2 MB bf16 x image
__device__ __align__(16) float g_P[(size_t)NROWS * 128];    // 4 MB fp32 partials

__device__ __forceinline__ u16 f2bf_rne(float f) {
    unsigned int u = __float_as_uint(f);
    u += 0x7fffu + ((u >> 16) & 1u);
    return (u16)(u >> 16);
}

// ---------------- prep: g_B[kt][o][kk] = B[kt*32+kk][o] via LDS transpose;
//                  also g_X = bf16(x), zero g_P ----------------
__global__ __launch_bounds__(256) void prep_kernel(
    const float* __restrict__ Ww, const float* __restrict__ Wb,
    const float* __restrict__ bw, const float* __restrict__ x)
{
    __shared__ __align__(16) u16 ls[32 * LS_STRIDE];
    const int kt = blockIdx.x;
    const int t  = threadIdx.x;

    if (kt < 512) {                       // zero g_P (8KB per block)
        const int zbase = (kt*256 + t) * 8;
        const floatx4 z = {0.f, 0.f, 0.f, 0.f};
        *(floatx4*)&g_P[zbase]     = z;
        *(floatx4*)&g_P[zbase + 4] = z;
        // convert x -> g_X bf16 (2048 elems per block)
        const int xb = kt*2048 + t*8;
        const floatx4 xa = *(const floatx4*)(x + xb);
        const floatx4 xc = *(const floatx4*)(x + xb + 4);
        ushort8 xw;
#pragma unroll
        for (int e = 0; e < 4; ++e) { xw[e] = f2bf_rne(xa[e]); xw[4+e] = f2bf_rne(xc[e]); }
        *(ushort8*)&g_X[xb] = xw;
    }

    float v[16];
    if (kt < 512) {
        const float* src = Ww + (size_t)(kt >> 2)*16384 + (size_t)(kt & 3)*32*128 + t*16;
#pragma unroll
        for (int c = 0; c < 4; ++c) {
            const floatx4 f4 = *(const floatx4*)(src + c*4);
#pragma unroll
            for (int e = 0; e < 4; ++e) v[c*4 + e] = f4[e];
        }
    } else {
        const size_t base = (size_t)(kt - 512)*32*128 + t*16;
#pragma unroll
        for (int c = 0; c < 4; ++c) {
            const floatx4 a = *(const floatx4*)(Wb + base + c*4);
            const floatx4 b = *(const floatx4*)(bw + base + c*4);
#pragma unroll
            for (int e = 0; e < 4; ++e) v[c*4 + e] = a[e] + b[e];
        }
    }
    {
        const int kk = t >> 3;
        const int o0 = (t & 7) * 16;
        ushort8 w0, w1;
#pragma unroll
        for (int e = 0; e < 8; ++e) { w0[e] = f2bf_rne(v[e]); w1[e] = f2bf_rne(v[8+e]); }
        *(ushort8*)&ls[kk*LS_STRIDE + o0]     = w0;
        *(ushort8*)&ls[kk*LS_STRIDE + o0 + 8] = w1;
    }
    __syncthreads();
    {
        const int o   = t >> 1;
        const int kk0 = (t & 1) * 16;
        ushort8 w0, w1;
#pragma unroll
        for (int e = 0; e < 8; ++e) {
            w0[e] = ls[(kk0 + e)*LS_STRIDE + o];
            w1[e] = ls[(kk0 + 8 + e)*LS_STRIDE + o];
        }
        u16* outp = g_B + (size_t)kt*TILE_E + t*16;
        ((ushort8*)outp)[0] = w0; ((ushort8*)outp)[1] = w1;
    }
}

// ---------------- gemm: depth-2 (pair) prefetch, single-round residency ----------------
// grid 1024: slice = b&7 (XCD-pinned), rb = (b>>3)&63, cg = b>>9. 4 blocks/CU.
__global__ __launch_bounds__(256, 4) void gemm_kernel()
{
    __shared__ __align__(16) u16 xs[BM * XS_STRIDE];

    const int b     = blockIdx.x;
    const int slice = b & 7;
    const int rb    = (b >> 3) & 63;
    const int cg    = b >> 9;
    const int row0  = rb * BM;
    const int tid   = threadIdx.x;
    const int lane  = tid & 63;
    const int wave  = tid >> 6;
    const int wm    = wave >> 1;
    const int wc    = wave & 1;
    const int l15   = lane & 15;
    const int q     = lane >> 4;

    // stage x rows from bf16 g_X (32 KB per block)
#pragma unroll
    for (int it = 0; it < 8; ++it) {
        const int c  = it*256 + tid;
        const int r  = c >> 4;
        const int c8 = (c & 15) * 8;
        *(ushort8*)&xs[r*XS_STRIDE + c8] =
            *(const ushort8*)&g_X[((size_t)(row0 + r) << 7) + c8];
    }
    __syncthreads();

    short8 af[4][4];                    // A[m=l15][k=q*8+e], phase-invariant
#pragma unroll
    for (int ks = 0; ks < 4; ++ks)
#pragma unroll
        for (int mt = 0; mt < 4; ++mt)
            af[ks][mt] = *(const short8*)&xs[(wm*64 + mt*16 + l15)*XS_STRIDE + ks*32 + q*8];

    const floatx4 fzero = {0.f, 0.f, 0.f, 0.f};
    floatx4 acc[4][2];
#pragma unroll
    for (int i = 0; i < 4; ++i) { acc[i][0] = fzero; acc[i][1] = fzero; }

    // phases: slice 0 -> 0..16 (17), slice s>0 -> 16s+1 .. +16; p=128 tail in slice 7
    const int p0 = slice*16 + (slice ? 1 : 0);
    const int np = (slice == 0) ? 17 : 16;

    const int colbase = cg*64 + wc*32;
    const size_t loff = (size_t)(colbase + l15)*32 + q*8;
    const int ktN = (p0 + np)*4;        // one past last kstep

    // load a PAIR of consecutive ksteps (4 frags = 16 VGPR)
    auto LOADP = [&](int ktp, short8 (&buf)[2][2]) {
        const u16* tb0 = g_B + (size_t)ktp*TILE_E + loff;
        buf[0][0] = *(const short8*)(tb0);
        buf[0][1] = *(const short8*)(tb0 + 512);
        const u16* tb1 = tb0 + TILE_E;
        buf[1][0] = *(const short8*)(tb1);
        buf[1][1] = *(const short8*)(tb1 + 512);
    };

    short8 bufA[2][2], bufB[2][2];
    int kt = p0*4;
    LOADP(kt, bufA);                    // pair (kt, kt+1)

    for (int pp = 0; pp < np; ++pp) {
        const int p = p0 + pp;
        floatx4 aj[4][2];
#pragma unroll
        for (int i = 0; i < 4; ++i) { aj[i][0] = fzero; aj[i][1] = fzero; }

        LOADP(kt + 2, bufB);            // prefetch pair 1 of this phase
#pragma unroll
        for (int s = 0; s < 2; ++s)
#pragma unroll
            for (int mt = 0; mt < 4; ++mt) {
                aj[mt][0] = __builtin_amdgcn_mfma_f32_16x16x32_bf16(af[s][mt], bufA[s][0], aj[mt][0], 0,0,0);
                aj[mt][1] = __builtin_amdgcn_mfma_f32_16x16x32_bf16(af[s][mt], bufA[s][1], aj[mt][1], 0,0,0);
            }
        const int ktn = (kt + 4 <= ktN - 2) ? kt + 4 : ktN - 2;
        LOADP(ktn, bufA);               // prefetch next phase's pair 0
#pragma unroll
        for (int s = 0; s < 2; ++s)
#pragma unroll
            for (int mt = 0; mt < 4; ++mt) {
                aj[mt][0] = __builtin_amdgcn_mfma_f32_16x16x32_bf16(af[2+s][mt], bufB[s][0], aj[mt][0], 0,0,0);
                aj[mt][1] = __builtin_amdgcn_mfma_f32_16x16x32_bf16(af[2+s][mt], bufB[s][1], aj[mt][1], 0,0,0);
            }
        kt += 4;

        // acc += x_bf16[row, p] * aj   (tail phase p==128: scale 1 -> Wb+bw term)
#pragma unroll
        for (int mt = 0; mt < 4; ++mt)
#pragma unroll
            for (int r = 0; r < 4; ++r) {
                const int rl = wm*64 + mt*16 + q*4 + r;     // C/D: row = q*4+reg
                float xj = 1.0f;
                if (p < 128)
                    xj = __uint_as_float(((unsigned int)xs[rl*XS_STRIDE + p]) << 16);
                acc[mt][0][r] += xj * aj[mt][0][r];
                acc[mt][1][r] += xj * aj[mt][1][r];
            }
    }

    // reduce into g_P (device-scope atomics)
#pragma unroll
    for (int mt = 0; mt < 4; ++mt)
#pragma unroll
        for (int nt = 0; nt < 2; ++nt) {
            const int col = colbase + nt*16 + l15;
#pragma unroll
            for (int r = 0; r < 4; ++r) {
                const int row = row0 + wm*64 + mt*16 + q*4 + r;
                atomicAdd(&g_P[((size_t)row << 7) + col], acc[mt][nt][r]);
            }
        }
}

// ---------------- finish: + bb, write fp32 ----------------
__global__ __launch_bounds__(256) void finish_kernel(
    const float* __restrict__ bb, float* __restrict__ out)
{
    const int flat = (blockIdx.x*256 + threadIdx.x) * 8;
    const floatx4 a = *(const floatx4*)&g_P[flat];
    const floatx4 c = *(const floatx4*)&g_P[flat + 4];
    const floatx4 b0 = *(const floatx4*)(bb + (flat & 127));
    const floatx4 b1 = *(const floatx4*)(bb + (flat & 127) + 4);
    floatx4 o0, o1;
#pragma unroll
    for (int e = 0; e < 4; ++e) { o0[e] = a[e] + b0[e]; o1[e] = c[e] + b1[e]; }
    *(floatx4*)(out + flat)     = o0;
    *(floatx4*)(out + flat + 4) = o1;
}

extern "C" void kernel_launch(void* const* d_in, const int* in_sizes, int n_in,
                              void* d_out, int out_size, void* d_ws, size_t ws_size,
                              hipStream_t stream) {
    (void)in_sizes; (void)n_in; (void)out_size; (void)d_ws; (void)ws_size;
    const float* x  = (const float*)d_in[0];
    const float* Wb = (const float*)d_in[1];
    const float* bb = (const float*)d_in[2];
    const float* Ww = (const float*)d_in[3];
    const float* bw = (const float*)d_in[4];
    float* out = (float*)d_out;

    prep_kernel  <<<dim3(NKT),            dim3(256), 0, stream>>>(Ww, Wb, bw, x);
    gemm_kernel  <<<dim3(1024),           dim3(256), 0, stream>>>();
    finish_kernel<<<dim3(NROWS*128/2048), dim3(256), 0, stream>>>(bb, out);
}